// Round 9
// baseline (131.705 us; speedup 1.0000x reference)
//
#include <hip/hip_runtime.h>

#define NC 20
#define NCELL 49
#define NGT 32
#define NIMG 8192
#define NTOT (NIMG * NCELL)        // 401408
#define CPB 128                    // cells per block (256 threads = 128 cells x 2 boxes)
#define NBLK (NTOT / CPB)          // 3136 blocks, exact
#define LAMBDA_COORD 5.0f
#define LAMBDA_NOOBJ 0.5f
#define EPS_IOU 1e-6f

// ---- d_ws layout (bytes); harness ws is >= 256 MB (poison fill = 262144 KB) ----
#define WS_CORNERS 0                              // float4[NIMG*NGT]  (4 MB)
#define WS_AREAS   (NIMG * NGT * 16)              // float [NIMG*NGT]  (1 MB)
#define WS_MASKS   (WS_AREAS + NIMG * NGT * 4)    // uint  [NIMG]      (32 KB)
#define WS_COUNTER (WS_MASKS + NIMG * 4)          // uint  (+ pad)
#define WS_PARTIAL (WS_COUNTER + 64)              // float [NBLK]

// Prep: corner-form GT + area + per-image multihot mask. All coalesced.
__global__ __launch_bounds__(256) void yolo_prep_kernel(
    const float* __restrict__ gt_boxes, const int* __restrict__ gt_labels,
    float4* __restrict__ corners, float* __restrict__ areas,
    unsigned* __restrict__ masks)
{
    const int t = blockIdx.x * 256 + threadIdx.x;       // < NIMG*NGT
    float4 b = reinterpret_cast<const float4*>(gt_boxes)[t];
    corners[t] = make_float4(fmaf(b.z, -0.5f, b.x), fmaf(b.w, -0.5f, b.y),
                             fmaf(b.z,  0.5f, b.x), fmaf(b.w,  0.5f, b.y));
    areas[t] = b.z * b.w;
    atomicOr(&masks[t >> 5], 1u << gt_labels[t]);
}

// Thread = (cell, box). Acts staged in LDS (coalesced); GT corners/areas/mask
// read from GLOBAL as L1-resident broadcasts (vector-mem pipe, unloading LDS).
// S-form argmax: S = pa+ga+eps; in/(S-in) monotone in in/S =>
// in_j*bS > bin*S_j orders identically to IoU. Init (-1,1): j=0 always wins,
// strict > => first-index argmax (jnp semantics).
__global__ __launch_bounds__(256, 8) void yolo_main_kernel(
    const float* __restrict__ outputs,      // [N, 49, 30]
    const float4* __restrict__ corners,     // [N*32]
    const float* __restrict__ areas,        // [N*32]
    const unsigned* __restrict__ masks,     // [N]
    float* __restrict__ partials,           // [NBLK]
    unsigned* __restrict__ counter,         // [1], zeroed per launch
    float* __restrict__ out)                // [1]
{
    __shared__ float4 s_act4[CPB * 30 / 4];      // 15360 B
    __shared__ float  s_w[4];
    __shared__ bool   s_last;

    const int tid = threadIdx.x;
    const unsigned base   = blockIdx.x * CPB;
    const unsigned img_lo = base / NCELL;
    const unsigned off    = base - img_lo * NCELL;      // 0..48

    // ---- stage activations: 960 float4, coalesced ----
    const float4* asrc = reinterpret_cast<const float4*>(outputs) + (size_t)base * 30 / 4;
    #pragma unroll
    for (int k = 0; k < 4; ++k) {
        int i = tid + k * 256;
        if (i < CPB * 30 / 4) s_act4[i] = asrc[i];
    }
    __syncthreads();

    // ---- per-thread: one (cell, box) ----
    const int p = tid & 1;
    const int s = tid >> 1;
    const unsigned rel  = ((unsigned)(s + off) * 1339u) >> 16;   // /49, arg<392
    const unsigned img  = img_lo + rel;
    const unsigned mask = masks[img];                    // L1 broadcast
    const float2* a2 = reinterpret_cast<const float2*>(s_act4) + s * 15;

    // ---- CE, split across the box pair (each thread: 10 classes) ----
    const float2* cp = a2 + 5 + p * 5;
    float2 c0 = cp[0], c1 = cp[1], c2 = cp[2], c3 = cp[3], c4 = cp[4];
    float mxh = fmaxf(fmaxf(fmaxf(c0.x, c0.y), fmaxf(c1.x, c1.y)),
                      fmaxf(fmaxf(c2.x, c2.y), fmaxf(c3.x, c3.y)));
    mxh = fmaxf(mxh, fmaxf(c4.x, c4.y));
    const unsigned mh = mask >> (p * 10);
    float selh = ((mh & 1u)   ? c0.x : 0.f) + ((mh & 2u)   ? c0.y : 0.f)
               + ((mh & 4u)   ? c1.x : 0.f) + ((mh & 8u)   ? c1.y : 0.f)
               + ((mh & 16u)  ? c2.x : 0.f) + ((mh & 32u)  ? c2.y : 0.f)
               + ((mh & 64u)  ? c3.x : 0.f) + ((mh & 128u) ? c3.y : 0.f)
               + ((mh & 256u) ? c4.x : 0.f) + ((mh & 512u) ? c4.y : 0.f);
    const float mx = fmaxf(mxh, __shfl_xor(mxh, 1));
    float ssh = __expf(c0.x - mx) + __expf(c0.y - mx)
              + __expf(c1.x - mx) + __expf(c1.y - mx)
              + __expf(c2.x - mx) + __expf(c2.y - mx)
              + __expf(c3.x - mx) + __expf(c3.y - mx)
              + __expf(c4.x - mx) + __expf(c4.y - mx);
    const float ssum = ssh + __shfl_xor(ssh, 1);
    const float sel  = selh + __shfl_xor(selh, 1);
    const float ce = (float)__popc(mask) * (mx + __logf(ssum)) - sel;

    // ---- my box: floats [5p .. 5p+4] of the cell record ----
    float2 A = a2[2 * p], Bv = a2[2 * p + 1], Cv = a2[2 * p + 2];
    const float cx = p ? A.y  : A.x;
    const float cy = p ? Bv.x : A.y;
    const float w  = p ? Bv.y : Bv.x;
    const float h  = p ? Cv.x : Bv.y;
    const float cf = p ? Cv.y : Cv.x;

    const float px1 = fmaf(w, -0.5f, cx), py1 = fmaf(h, -0.5f, cy);
    const float px2 = fmaf(w,  0.5f, cx), py2 = fmaf(h,  0.5f, cy);
    const float pae = w * h + EPS_IOU;

    // ---- IoU argmax over 32 GTs: global L1 broadcast reads ----
    const float4* gc  = corners + (size_t)img * NGT;
    const float4* ga4 = reinterpret_cast<const float4*>(areas + (size_t)img * NGT);
    float bin = -1.f, bS = 1.f;
    int bi = 0;
    #pragma unroll 1
    for (int jc = 0; jc < NGT; jc += 4) {
        float4 g0 = gc[jc], g1 = gc[jc + 1], g2 = gc[jc + 2], g3 = gc[jc + 3];
        float4 ar = ga4[jc >> 2];
        {
            float iw = fmaxf(fminf(px2, g0.z) - fmaxf(px1, g0.x), 0.f);
            float ih = fmaxf(fminf(py2, g0.w) - fmaxf(py1, g0.y), 0.f);
            float in = iw * ih, S = pae + ar.x;
            if (in * bS > bin * S) { bin = in; bS = S; bi = jc; }
        }
        {
            float iw = fmaxf(fminf(px2, g1.z) - fmaxf(px1, g1.x), 0.f);
            float ih = fmaxf(fminf(py2, g1.w) - fmaxf(py1, g1.y), 0.f);
            float in = iw * ih, S = pae + ar.y;
            if (in * bS > bin * S) { bin = in; bS = S; bi = jc + 1; }
        }
        {
            float iw = fmaxf(fminf(px2, g2.z) - fmaxf(px1, g2.x), 0.f);
            float ih = fmaxf(fminf(py2, g2.w) - fmaxf(py1, g2.y), 0.f);
            float in = iw * ih, S = pae + ar.z;
            if (in * bS > bin * S) { bin = in; bS = S; bi = jc + 2; }
        }
        {
            float iw = fmaxf(fminf(px2, g3.z) - fmaxf(px1, g3.x), 0.f);
            float ih = fmaxf(fminf(py2, g3.w) - fmaxf(py1, g3.y), 0.f);
            float in = iw * ih, S = pae + ar.w;
            if (in * bS > bin * S) { bin = in; bS = S; bi = jc + 3; }
        }
    }

    // ---- loss term (matched mid/dims recovered from corners) ----
    float term;
    if (bin > 0.f) {
        float4 g = gc[bi];                               // L1 hit
        const float iou = __fdividef(bin, bS - bin);
        const float dx = cx - (g.x + g.z) * 0.5f;
        const float dy = cy - (g.y + g.w) * 0.5f;
        const float dw = sqrtf(w) - sqrtf(g.z - g.x);
        const float dh = sqrtf(h) - sqrtf(g.w - g.y);
        term = LAMBDA_COORD * (dx * dx + dy * dy + dw * dw + dh * dh)
             + (cf - iou) * (cf - iou) + ce;
    } else {
        term = LAMBDA_NOOBJ * cf * cf;
    }

    // ---- block reduce -> partials[block] ----
    float partial = term;
    #pragma unroll
    for (int o = 32; o > 0; o >>= 1)
        partial += __shfl_down(partial, o);
    if ((tid & 63) == 0) s_w[tid >> 6] = partial;
    __syncthreads();
    if (tid == 0) {
        partials[blockIdx.x] = s_w[0] + s_w[1] + s_w[2] + s_w[3];
        __threadfence();                                 // publish partial
        unsigned prev = atomicAdd(counter, 1u);
        s_last = (prev == NBLK - 1);
    }
    __syncthreads();

    // ---- last finishing block sums all partials and writes the output ----
    if (s_last) {
        __threadfence();                                 // acquire partials
        float sum = 0.f;
        for (int i = tid; i < NBLK; i += 256) sum += partials[i];
        #pragma unroll
        for (int o = 32; o > 0; o >>= 1)
            sum += __shfl_down(sum, o);
        if ((tid & 63) == 0) s_w[tid >> 6] = sum;
        __syncthreads();
        if (tid == 0)
            out[0] = (s_w[0] + s_w[1] + s_w[2] + s_w[3]) * (1.0f / (float)NIMG);
    }
}

extern "C" void kernel_launch(void* const* d_in, const int* in_sizes, int n_in,
                              void* d_out, int out_size, void* d_ws, size_t ws_size,
                              hipStream_t stream) {
    const float* outputs   = (const float*)d_in[0];
    const float* gt_boxes  = (const float*)d_in[1];
    const int*   gt_labels = (const int*)d_in[2];
    float* out = (float*)d_out;

    char* ws = (char*)d_ws;
    float4*   corners  = (float4*)(ws + WS_CORNERS);
    float*    areas    = (float*)(ws + WS_AREAS);
    unsigned* masks    = (unsigned*)(ws + WS_MASKS);
    unsigned* counter  = (unsigned*)(ws + WS_COUNTER);
    float*    partials = (float*)(ws + WS_PARTIAL);

    // zero masks + counter (contiguous region), graph-capture-safe
    hipMemsetAsync(ws + WS_MASKS, 0, NIMG * 4 + 64, stream);
    yolo_prep_kernel<<<NIMG * NGT / 256, 256, 0, stream>>>(gt_boxes, gt_labels,
                                                           corners, areas, masks);
    yolo_main_kernel<<<NBLK, 256, 0, stream>>>(outputs, corners, areas, masks,
                                               partials, counter, out);
}

// Round 10
// 33.549 us; speedup vs baseline: 3.9258x; 3.9258x over previous
//
#include <hip/hip_runtime.h>

#define NC 20
#define NCELL 49
#define NGT 32
#define NIMG 8192
#define NTOT (NIMG * NCELL)        // 401408
#define CPB 128                    // cells per block (256 threads = 128 cells x 2 boxes)
#define NBLK (NTOT / CPB)          // 3136 blocks, exact
#define NSPAN 4                    // images spanned by 128 consecutive cells
#define LAMBDA_COORD 5.0f
#define LAMBDA_NOOBJ 0.5f
#define EPS_IOU 1e-6f

// Thread = (cell, box p). NEW vs R6: each thread scans only GT chunk
// [16p, 16p+16) but against BOTH boxes of its cell; a shfl_xor(1) exchange
// merges the per-chunk argmaxes. Halves GT LDS reads; VALU total unchanged.
// S-form argmax: S = pa+ga+eps; in/(S-in) monotone in in/S =>
// in_j*bS > bin*S_j orders identically to IoU. Init (-1,1): first GT of the
// chunk always wins; strict > => first-index within chunk; cross-chunk merge
// prefers chunk0 on ties (>= for p=1, > for p=0) => global first-index.
__global__ __launch_bounds__(256, 8) void yolo_main_kernel(
    const float* __restrict__ outputs,     // [N, 49, 30]
    const float* __restrict__ gt_boxes,    // [N, 32, 4]
    const int*   __restrict__ gt_labels,   // [N, 32]
    float* __restrict__ partials)          // [NBLK]
{
    __shared__ float4   s_act4[CPB * 30 / 4];    // 15360 B
    __shared__ float4   s_gtc[NSPAN * NGT];      //  2048 B: x1,y1,x2,y2
    __shared__ float4   s_ga4[NSPAN * NGT / 4];  //   512 B: areas (16B aligned)
    __shared__ unsigned s_mask[NSPAN];
    __shared__ float    s_w[4];

    const int tid = threadIdx.x;
    const unsigned base   = blockIdx.x * CPB;
    const unsigned img_lo = base / NCELL;
    const unsigned off    = base - img_lo * NCELL;   // 0..48

    if (tid < NSPAN) s_mask[tid] = 0u;
    __syncthreads();

    // ---- stage GT (threads 0..127) and labels (threads 128..255) ----
    if (tid < 128) {
        const unsigned g   = tid >> 5;
        const unsigned img = img_lo + g;
        if (img < NIMG) {
            float4 b = reinterpret_cast<const float4*>(gt_boxes)[img * NGT + (tid & 31)];
            s_gtc[tid] = make_float4(fmaf(b.z, -0.5f, b.x), fmaf(b.w, -0.5f, b.y),
                                     fmaf(b.z,  0.5f, b.x), fmaf(b.w,  0.5f, b.y));
            reinterpret_cast<float*>(s_ga4)[tid] = b.z * b.w;
        }
    } else {
        const int t = tid - 128;
        const unsigned g   = t >> 5;
        const unsigned img = img_lo + g;
        if (img < NIMG) {
            int lab = gt_labels[img * NGT + (t & 31)];
            atomicOr(&s_mask[g], 1u << lab);
        }
    }

    // ---- stage activations: 960 float4, coalesced ----
    const float4* asrc = reinterpret_cast<const float4*>(outputs) + (size_t)base * 30 / 4;
    #pragma unroll
    for (int k = 0; k < 4; ++k) {
        int i = tid + k * 256;
        if (i < CPB * 30 / 4) s_act4[i] = asrc[i];
    }
    __syncthreads();

    // ---- per-thread: one (cell, box p) ----
    const int p = tid & 1;
    const int s = tid >> 1;
    const unsigned rel  = ((unsigned)(s + off) * 1339u) >> 16;   // /49, arg<392
    const unsigned mask = s_mask[rel];
    const float2* a2 = reinterpret_cast<const float2*>(s_act4) + s * 15;

    // ---- CE, split across the box pair (each thread: 10 classes) ----
    const float2* cp = a2 + 5 + p * 5;
    float2 c0 = cp[0], c1 = cp[1], c2 = cp[2], c3 = cp[3], c4 = cp[4];
    float mxh = fmaxf(fmaxf(fmaxf(c0.x, c0.y), fmaxf(c1.x, c1.y)),
                      fmaxf(fmaxf(c2.x, c2.y), fmaxf(c3.x, c3.y)));
    mxh = fmaxf(mxh, fmaxf(c4.x, c4.y));
    const unsigned mh = mask >> (p * 10);
    float selh = ((mh & 1u)   ? c0.x : 0.f) + ((mh & 2u)   ? c0.y : 0.f)
               + ((mh & 4u)   ? c1.x : 0.f) + ((mh & 8u)   ? c1.y : 0.f)
               + ((mh & 16u)  ? c2.x : 0.f) + ((mh & 32u)  ? c2.y : 0.f)
               + ((mh & 64u)  ? c3.x : 0.f) + ((mh & 128u) ? c3.y : 0.f)
               + ((mh & 256u) ? c4.x : 0.f) + ((mh & 512u) ? c4.y : 0.f);
    const float mx = fmaxf(mxh, __shfl_xor(mxh, 1));
    float ssh = __expf(c0.x - mx) + __expf(c0.y - mx)
              + __expf(c1.x - mx) + __expf(c1.y - mx)
              + __expf(c2.x - mx) + __expf(c2.y - mx)
              + __expf(c3.x - mx) + __expf(c3.y - mx)
              + __expf(c4.x - mx) + __expf(c4.y - mx);
    const float ssum = ssh + __shfl_xor(ssh, 1);
    const float sel  = selh + __shfl_xor(selh, 1);
    const float ce = (float)__popc(mask) * (mx + __logf(ssum)) - sel;

    // ---- BOTH boxes' registers (GT chunk is evaluated against both) ----
    float2 q0 = a2[0], q1 = a2[1], q2 = a2[2], q3 = a2[3], q4 = a2[4];
    const float cx0 = q0.x, cy0 = q0.y, w0 = q1.x, h0 = q1.y, cf0 = q2.x;
    const float cx1 = q2.y, cy1 = q3.x, w1 = q3.y, h1 = q4.x, cf1 = q4.y;
    const float px1_0 = fmaf(w0, -0.5f, cx0), py1_0 = fmaf(h0, -0.5f, cy0);
    const float px2_0 = fmaf(w0,  0.5f, cx0), py2_0 = fmaf(h0,  0.5f, cy0);
    const float px1_1 = fmaf(w1, -0.5f, cx1), py1_1 = fmaf(h1, -0.5f, cy1);
    const float px2_1 = fmaf(w1,  0.5f, cx1), py2_1 = fmaf(h1,  0.5f, cy1);
    const float pa0e = w0 * h0 + EPS_IOU, pa1e = w1 * h1 + EPS_IOU;

    // ---- my 16-GT chunk vs both boxes ----
    const float4* gtc = s_gtc + rel * NGT;
    const float4* gmy = gtc + p * 16;
    const float4* amy = s_ga4 + rel * (NGT / 4) + p * 4;
    float bin0 = -1.f, bS0 = 1.f, bin1 = -1.f, bS1 = 1.f;
    int bi0 = 0, bi1 = 0;
    #pragma unroll
    for (int jc = 0; jc < 16; jc += 4) {
        float4 g0 = gmy[jc], g1 = gmy[jc + 1], g2 = gmy[jc + 2], g3 = gmy[jc + 3];
        float4 ar = amy[jc >> 2];
        #define UPD2(g, ga_, j_) do {                                           \
            float iw0 = fmaxf(fminf(px2_0, (g).z) - fmaxf(px1_0, (g).x), 0.f);  \
            float ih0 = fmaxf(fminf(py2_0, (g).w) - fmaxf(py1_0, (g).y), 0.f);  \
            float in0 = iw0 * ih0, S0 = pa0e + (ga_);                           \
            if (in0 * bS0 > bin0 * S0) { bin0 = in0; bS0 = S0; bi0 = (j_); }    \
            float iw1 = fmaxf(fminf(px2_1, (g).z) - fmaxf(px1_1, (g).x), 0.f);  \
            float ih1 = fmaxf(fminf(py2_1, (g).w) - fmaxf(py1_1, (g).y), 0.f);  \
            float in1 = iw1 * ih1, S1 = pa1e + (ga_);                           \
            if (in1 * bS1 > bin1 * S1) { bin1 = in1; bS1 = S1; bi1 = (j_); }    \
        } while (0)
        UPD2(g0, ar.x, jc);
        UPD2(g1, ar.y, jc + 1);
        UPD2(g2, ar.z, jc + 2);
        UPD2(g3, ar.w, jc + 3);
    }

    // ---- exchange the other box's chunk-state; merge (chunk0 preferred) ----
    const float oin = p ? bin1 : bin0;          // own box, own chunk
    const float oS  = p ? bS1  : bS0;
    const int   obi = p * 16 + (p ? bi1 : bi0); // global GT index
    const float sin_ = p ? bin0 : bin1;         // other box, own chunk (send)
    const float sS   = p ? bS0  : bS1;
    const int   sbi  = p * 16 + (p ? bi0 : bi1);
    const float rin = __shfl_xor(sin_, 1);      // own box, other chunk (recv)
    const float rS  = __shfl_xor(sS, 1);
    const int   rbi = __shfl_xor(sbi, 1);
    // p=0: own=chunk0, recv=chunk1 -> take recv iff strictly greater.
    // p=1: own=chunk1, recv=chunk0 -> take recv iff greater-or-equal.
    const float a_ = rin * oS, b_ = oin * rS;
    const bool take = p ? (a_ >= b_) : (a_ > b_);
    const float bin = take ? rin : oin;
    const float bS  = take ? rS  : oS;
    const int   bi  = take ? rbi : obi;

    // ---- own box scalars for the epilogue ----
    const float cx = p ? cx1 : cx0, cy = p ? cy1 : cy0;
    const float w  = p ? w1  : w0,  h  = p ? h1  : h0;
    const float cf = p ? cf1 : cf0;

    float term;
    if (bin > 0.f) {
        float4 g = gtc[bi];                      // broadcast LDS read
        const float iou = __fdividef(bin, bS - bin);
        const float dx = cx - (g.x + g.z) * 0.5f;
        const float dy = cy - (g.y + g.w) * 0.5f;
        const float dw = sqrtf(w) - sqrtf(g.z - g.x);
        const float dh = sqrtf(h) - sqrtf(g.w - g.y);
        term = LAMBDA_COORD * (dx * dx + dy * dy + dw * dw + dh * dh)
             + (cf - iou) * (cf - iou) + ce;
    } else {
        term = LAMBDA_NOOBJ * cf * cf;
    }

    // ---- block reduce -> 1 float per block ----
    float partial = term;
    #pragma unroll
    for (int o = 32; o > 0; o >>= 1)
        partial += __shfl_down(partial, o);
    if ((tid & 63) == 0) s_w[tid >> 6] = partial;
    __syncthreads();
    if (tid == 0)
        partials[blockIdx.x] = s_w[0] + s_w[1] + s_w[2] + s_w[3];
}

__global__ __launch_bounds__(256) void yolo_reduce_kernel(
    const float* __restrict__ partials, float* __restrict__ out)
{
    float s = 0.f;
    for (int i = threadIdx.x; i < NBLK; i += 256) s += partials[i];
    #pragma unroll
    for (int o = 32; o > 0; o >>= 1)
        s += __shfl_down(s, o);
    __shared__ float s_w[4];
    const int tid = threadIdx.x;
    if ((tid & 63) == 0) s_w[tid >> 6] = s;
    __syncthreads();
    if (tid == 0)
        out[0] = (s_w[0] + s_w[1] + s_w[2] + s_w[3]) * (1.0f / (float)NIMG);
}

extern "C" void kernel_launch(void* const* d_in, const int* in_sizes, int n_in,
                              void* d_out, int out_size, void* d_ws, size_t ws_size,
                              hipStream_t stream) {
    const float* outputs   = (const float*)d_in[0];
    const float* gt_boxes  = (const float*)d_in[1];
    const int*   gt_labels = (const int*)d_in[2];
    float* out      = (float*)d_out;
    float* partials = (float*)d_ws;          // NBLK floats = 12.5 KB

    yolo_main_kernel<<<NBLK, 256, 0, stream>>>(outputs, gt_boxes, gt_labels, partials);
    yolo_reduce_kernel<<<1, 256, 0, stream>>>(partials, out);
}